// Round 7
// baseline (252.672 us; speedup 1.0000x reference)
//
#include <hip/hip_runtime.h>

typedef __bf16 bf16x8 __attribute__((ext_vector_type(8)));
typedef float f32x4 __attribute__((ext_vector_type(4)));

#define EPS_F 1e-5f

__device__ __forceinline__ unsigned short cvtbf(float f) {
    __bf16 h = (__bf16)f;              // RNE fptrunc
    unsigned short u;
    __builtin_memcpy(&u, &h, 2);
    return u;
}

// -------------------------------------------------------------------------
// Kernel 0: w1 fp32 -> bf16 once (kills 134M per-launch cvts in k1).
// 256*1024 = 262144 elems; 128 blocks x 256 thr x 8.
// -------------------------------------------------------------------------
__global__ __launch_bounds__(256) void k_cvt_w1(
    const float* __restrict__ w1, unsigned short* __restrict__ w1b)
{
    const int idx = (blockIdx.x * 256 + threadIdx.x) * 8;
    const float4 f0 = *(const float4*)(w1 + idx);
    const float4 f1 = *(const float4*)(w1 + idx + 4);
    ushort4 o0, o1;
    o0.x = cvtbf(f0.x); o0.y = cvtbf(f0.y); o0.z = cvtbf(f0.z); o0.w = cvtbf(f0.w);
    o1.x = cvtbf(f1.x); o1.y = cvtbf(f1.y); o1.z = cvtbf(f1.z); o1.w = cvtbf(f1.w);
    *(ushort4*)(w1b + idx)     = o0;
    *(ushort4*)(w1b + idx + 4) = o1;
}

// -------------------------------------------------------------------------
// Kernel 1 (MFMA, M-split): partial pooled sums for 49 positions.
// grid (128 b, 4 pc), block 512 (8 waves: 2m x 4n).
// Per block: M=49(pad 64, 4 m-tiles) x N=256 (16 n-tiles) x K=1024, BK=32.
// x read EXACTLY once across the grid (was 4x); w1b re-read from L2.
// pooled_part[pc][b][r] = sum_{p in chunk} hardswish(BN(h[r][p]))
// -------------------------------------------------------------------------
__global__ __launch_bounds__(512) void k_gemm_pool(
    const float* __restrict__ x,
    const unsigned short* __restrict__ w1b,
    const float* __restrict__ g1,
    const float* __restrict__ b1,
    const float* __restrict__ m1,
    const float* __restrict__ v1,
    float* __restrict__ pooled_part)
{
    constexpr int LDK = 36;                      // padded k-stride (bf16)
    __shared__ unsigned short Alds[64 * LDK];    // [m=p][k]   4.6 KiB
    __shared__ unsigned short Blds[256 * LDK];   // [n=r][k]  18.4 KiB
    __shared__ float pool_sc[2][256];

    const int b   = blockIdx.x;
    const int pc  = blockIdx.y;
    const int p0  = pc * 49;
    const int tid = threadIdx.x;
    const int wave = tid >> 6, lane = tid & 63;
    const int wm = wave >> 2, wn = wave & 3;     // 2(m) x 4(n)
    const int q  = lane >> 4, ln = lane & 15;

    f32x4 acc[2][4];
#pragma unroll
    for (int i = 0; i < 2; i++)
#pragma unroll
        for (int j = 0; j < 4; j++) acc[i][j] = (f32x4){0.f, 0.f, 0.f, 0.f};

    // A-stage roles: cl = k-row within BK (32), psub = position sub-index (16)
    const int cl = tid >> 4, psub = tid & 15;
    const float* xa = x + ((size_t)b * 1024 + cl) * 196 + p0 + psub;
    // B-stage roles: 2 threads per r-row, 16 k each (32 B copy)
    const int rb = tid >> 1, kh = (tid & 1) * 16;
    const unsigned short* wrow = w1b + rb * 1024 + kh;

    for (int kc = 0; kc < 1024; kc += 32) {
        __syncthreads();
        // ---- stage B: straight bf16 copy ----
        {
            const uint4 v0 = *(const uint4*)(wrow + kc);
            const uint4 v1 = *(const uint4*)(wrow + kc + 8);
            *(uint4*)&Blds[rb * LDK + kh]     = v0;
            *(uint4*)&Blds[rb * LDK + kh + 8] = v1;
        }
        // ---- stage A: fp32 -> bf16, transpose [c][p] -> [p][c] ----
        {
            const float* xi = xa + (size_t)kc * 196;
#pragma unroll
            for (int j = 0; j < 4; j++) {
                const int p = psub + j * 16;
                if (p < 49)
                    Alds[p * LDK + cl] = cvtbf(xi[j * 16]);
            }
        }
        __syncthreads();
        // ---- MFMA: 2 m-tiles x 4 n-tiles per wave ----
        bf16x8 bfr[4], afr[2];
#pragma unroll
        for (int ni = 0; ni < 4; ni++)
            bfr[ni] = *(const bf16x8*)&Blds[(wn * 64 + ni * 16 + ln) * LDK + q * 8];
#pragma unroll
        for (int mi = 0; mi < 2; mi++)
            afr[mi] = *(const bf16x8*)&Alds[(wm * 32 + mi * 16 + ln) * LDK + q * 8];
#pragma unroll
        for (int mi = 0; mi < 2; mi++)
#pragma unroll
            for (int ni = 0; ni < 4; ni++)
                acc[mi][ni] = __builtin_amdgcn_mfma_f32_16x16x32_bf16(
                    afr[mi], bfr[ni], acc[mi][ni], 0, 0, 0);
    }

    // ---- epilogue: BN + hardswish + partial pool (mask p_local >= 49) ----
    float psum[4] = {0.f, 0.f, 0.f, 0.f};
#pragma unroll
    for (int ni = 0; ni < 4; ni++) {
        const int r = wn * 64 + ni * 16 + ln;
        const float s1 = g1[r] * rsqrtf(v1[r] + EPS_F);
        const float mu = m1[r];
        const float be = b1[r];
#pragma unroll
        for (int mi = 0; mi < 2; mi++)
#pragma unroll
            for (int i = 0; i < 4; i++) {
                const int pl = wm * 32 + mi * 16 + q * 4 + i;  // C/D row
                if (pl < 49) {
                    float v = acc[mi][ni][i];
                    v = (v - mu) * s1 + be;
                    const float g = fminf(fmaxf(v + 3.f, 0.f), 6.f);
                    psum[ni] += v * g * (1.f / 6.f);
                }
            }
    }
#pragma unroll
    for (int ni = 0; ni < 4; ni++) {
        psum[ni] += __shfl_xor(psum[ni], 16, 64);
        psum[ni] += __shfl_xor(psum[ni], 32, 64);
        if (lane < 16) pool_sc[wm][wn * 64 + ni * 16 + lane] = psum[ni];
    }
    __syncthreads();
    if (tid < 256)
        pooled_part[((size_t)pc * 128 + b) * 256 + tid] =
            pool_sc[0][tid] + pool_sc[1][tid];
}

__device__ __forceinline__ void prep1(float s, float e, int n, int size, int i,
                                      int& lo, int& hi, float& w0, float& w1)
{
    const float bsz = (e - s) / (float)n;
    float c = s + ((float)i + 0.5f) * bsz;
    const float valid = (c >= -1.f && c <= (float)size) ? 1.f : 0.f;
    c = fminf(fmaxf(c, 0.f), (float)(size - 1));
    lo = (int)floorf(c);
    hi = min(lo + 1, size - 1);
    const float f = c - (float)lo;
    w0 = (1.f - f) * valid;
    w1 = f * valid;
}

// -------------------------------------------------------------------------
// Kernel 2: fused logits+ROI-align. grid (128 b, 32 cgrp), block 320.
// Prelude: redundantly compute roi[b] from pooled_part (kills k_logits).
// Thread <-> po (fixed): 8 (offset,weight) pairs live in REGISTERS;
// loop over 8 channels -> 8 LDS reads + 8 FMA per output.
// -------------------------------------------------------------------------
__global__ __launch_bounds__(320) void k_roi(
    const float* __restrict__ x,
    const float* __restrict__ pooled_part,
    const float* __restrict__ w2,
    const float* __restrict__ g2,
    const float* __restrict__ b2,
    const float* __restrict__ m2,
    const float* __restrict__ v2,
    float* __restrict__ out)
{
    __shared__ float xs[32 * 200];   // 32 ch x 196 (pad 200)  25.6 KiB
    __shared__ float red[6][4];
    __shared__ float roi_s[6];

    const int b = blockIdx.x, c0 = blockIdx.y * 32;
    const int tid = threadIdx.x;
    const int wave = tid >> 6, lane = tid & 63;

    // ---- stage 32 channels, coalesced float4 (196 = 49*4; rows 16B-aligned) ----
    const float* xb = x + ((size_t)b * 1024 + c0) * 196;
#pragma unroll
    for (int k = 0; k < 5; k++) {
        const int i4 = tid + k * 320;
        if (i4 < 1568) {                       // 32*49
            const int c = i4 / 49, pq = i4 - c * 49;
            const float4 v = *(const float4*)(xb + c * 196 + pq * 4);
            *(float4*)&xs[c * 200 + pq * 4] = v;
        }
    }
    // ---- prelude: logits from pooled_part (redundant per block, cheap) ----
    float part[6] = {0.f, 0.f, 0.f, 0.f, 0.f, 0.f};
    if (tid < 256) {
        const size_t o = (size_t)b * 256 + tid;
        const float pv = (pooled_part[o] + pooled_part[32768 + o] +
                          pooled_part[65536 + o] + pooled_part[98304 + o]) *
                         (1.f / 196.f);
#pragma unroll
        for (int j = 0; j < 6; j++) part[j] = pv * w2[j * 256 + tid];
    }
#pragma unroll
    for (int j = 0; j < 6; j++)
#pragma unroll
        for (int off = 32; off >= 1; off >>= 1)
            part[j] += __shfl_xor(part[j], off, 64);
    if (lane == 0 && wave < 4)
#pragma unroll
        for (int j = 0; j < 6; j++) red[j][wave] = part[j];
    __syncthreads();
    if (tid == 0) {
        const float SC[3] = {7.f, 7.f, 4.f};
#pragma unroll
        for (int j = 0; j < 6; j++) {
            float l = red[j][0] + red[j][1] + red[j][2] + red[j][3];
            const float s = g2[j] * rsqrtf(v2[j] + EPS_F);
            l = (l - m2[j]) * s + b2[j];
            const float raw = 1.f / (1.f + expf(-l));
            const int d = (j < 3) ? j : j - 3;
            roi_s[j] = (j < 3) ? 0.5f * raw * SC[d]
                               : (1.f - 0.5f * raw) * SC[d];
        }
    }
    __syncthreads();

    // ---- per-thread (po-fixed) interp table in registers ----
    const int po = tid % 80;       // active if < 75
    const int cg = tid / 80;       // 0..3, 8 channels each
    int   offr[8];
    float wtr[8];
    if (po < 75) {
        const int to = po / 25, rem = po % 25, yo = rem / 5, xo = rem % 5;
        int tl, th, yl, yh, xl, xh;
        float tw0, tw1, yw0, yw1, xw0, xw1;
        prep1(roi_s[2], roi_s[5], 3, 4, to, tl, th, tw0, tw1);  // t
        prep1(roi_s[1], roi_s[4], 5, 7, yo, yl, yh, yw0, yw1);  // y
        prep1(roi_s[0], roi_s[3], 5, 7, xo, xl, xh, xw0, xw1);  // x
#pragma unroll
        for (int s = 0; s < 8; s++) {
            const int   ti = (s & 4) ? th : tl;
            const int   yi = (s & 2) ? yh : yl;
            const int   xi = (s & 1) ? xh : xl;
            offr[s] = ti * 49 + yi * 7 + xi;
            wtr[s]  = ((s & 4) ? tw1 : tw0) *
                      ((s & 2) ? yw1 : yw0) *
                      ((s & 1) ? xw1 : xw0);
        }
    }
    // ---- main: 8 channels per thread ----
    if (po < 75) {
        const size_t obase = ((size_t)b * 1024 + c0 + cg * 8) * 75 + po;
#pragma unroll
        for (int k = 0; k < 8; k++) {
            const float* row = &xs[(cg * 8 + k) * 200];
            float v = 0.f;
#pragma unroll
            for (int s = 0; s < 8; s++)
                v += wtr[s] * row[offr[s]];
            out[obase + (size_t)k * 75] = v;
        }
    }
}

extern "C" void kernel_launch(void* const* d_in, const int* in_sizes, int n_in,
                              void* d_out, int out_size, void* d_ws, size_t ws_size,
                              hipStream_t stream)
{
    const float* x  = (const float*)d_in[0];
    const float* w1 = (const float*)d_in[1];
    const float* g1 = (const float*)d_in[2];
    const float* b1 = (const float*)d_in[3];
    const float* m1 = (const float*)d_in[4];
    const float* v1 = (const float*)d_in[5];
    const float* w2 = (const float*)d_in[6];
    const float* g2 = (const float*)d_in[7];
    const float* b2 = (const float*)d_in[8];
    const float* m2 = (const float*)d_in[9];
    const float* v2 = (const float*)d_in[10];

    unsigned short* w1b   = (unsigned short*)d_ws;           // 256K bf16 = 512 KB
    float* pooled_part    = (float*)((char*)d_ws + 524288);  // 4*128*256 f32 = 512 KB
    float* out            = (float*)d_out;

    k_cvt_w1<<<128, 256, 0, stream>>>(w1, w1b);
    k_gemm_pool<<<dim3(128, 4), 512, 0, stream>>>(x, w1b, g1, b1, m1, v1, pooled_part);
    k_roi<<<dim3(128, 32), 320, 0, stream>>>(x, pooled_part, w2, g2, b2, m2, v2, out);
}